// Round 3
// baseline (63.022 us; speedup 1.0000x reference)
//
#include <hip/hip_runtime.h>
#include <cstdint>
#include <cstddef>

typedef __attribute__((ext_vector_type(8))) short short8;
typedef __attribute__((ext_vector_type(4))) unsigned short ushort4_t;
typedef __attribute__((ext_vector_type(4))) float f32x4;

#define NF 40
#define NK 780           // 40*39/2 pairs
#define BT 16            // batch rows per block
#define THREADS 512      // 8 waves
#define KSPLIT 2         // k-range halves -> grid 1024 -> 3 blocks/CU (LDS-bound)

__device__ __forceinline__ unsigned short f2bf(float f) {
    unsigned int u = __float_as_uint(f);
    u = (u + 0x7fffu + ((u >> 16) & 1u)) >> 16;
    return (unsigned short)u;
}
__device__ __forceinline__ float bf2f(unsigned short x) {
    return __uint_as_float(((unsigned int)x) << 16);
}

// wfrag[k][half][l][t] = bf16( W[k][ (l&15)+16*half ][ 8*(l>>4)+t ] )
// A-fragment for mfma_f32_16x16x32_bf16 computing tmp[e,b] = sum_f W[e,f] vj[b,f]:
// rows m = e (split in two halves), K-dim = f. No LDS round-trip: each lane reads
// 32B of contiguous W (rows tiled 4 lanes x 32B = perfectly coalesced).
__global__ __launch_bounds__(128) void wprep_kernel(const float* __restrict__ W,
                                                    unsigned short* __restrict__ wfrag) {
    const int k = blockIdx.x, t = threadIdx.x;
    const int half = t >> 6, l = t & 63;
    const int e = (l & 15) + 16 * half;
    const int f0 = 8 * (l >> 4);
    const float* src = W + (size_t)k * 1024 + e * 32 + f0;
    const float4 x0 = *(const float4*)src;
    const float4 x1 = *(const float4*)(src + 4);
    short8 v;
    v[0] = (short)f2bf(x0.x); v[1] = (short)f2bf(x0.y);
    v[2] = (short)f2bf(x0.z); v[3] = (short)f2bf(x0.w);
    v[4] = (short)f2bf(x1.x); v[5] = (short)f2bf(x1.y);
    v[6] = (short)f2bf(x1.z); v[7] = (short)f2bf(x1.w);
    *(short8*)(wfrag + (size_t)k * 1024 + half * 512 + l * 8) = v;
}

// embT granule (field, g) holds bf16 of emb[b0+b][field][8*fq .. 8*fq+7], where
// g = (b + 16*fq) ^ (field & 7). The XOR spreads staging writes across all 8
// bank-quads (fixes the 32-way conflict); reads apply the same XOR.
__global__ __launch_bounds__(THREADS) void bil_kernel(const float* __restrict__ emb,
                                                      const unsigned short* __restrict__ wfrag,
                                                      float* __restrict__ out) {
    __shared__ __align__(16) char embT[NF * 1024];      // 40960 B
    __shared__ unsigned int ijA[NK];                    // 3120 B

    const int tid = threadIdx.x;
    const int btile = blockIdx.x >> 1;
    const int khalf = blockIdx.x & 1;
    const int b0 = btile * BT;

    // --- Stage embedding tile: coalesced 32B global reads, conflict-free 16B LDS writes ---
    for (int u = tid; u < BT * 160; u += THREADS) {     // exactly 5 iterations
        const int bb = u / 160;
        const int t = u - 160 * bb;
        const int field = t >> 2;
        const int fq = t & 3;
        const float* src = emb + (size_t)(b0 + bb) * (NF * 32) + field * 32 + 8 * fq;
        const float4 x0 = *(const float4*)src;
        const float4 x1 = *(const float4*)(src + 4);
        short8 v;
        v[0] = (short)f2bf(x0.x); v[1] = (short)f2bf(x0.y);
        v[2] = (short)f2bf(x0.z); v[3] = (short)f2bf(x0.w);
        v[4] = (short)f2bf(x1.x); v[5] = (short)f2bf(x1.y);
        v[6] = (short)f2bf(x1.z); v[7] = (short)f2bf(x1.w);
        const int g = (bb + 16 * fq) ^ (field & 7);
        *(short8*)(embT + field * 1024 + g * 16) = v;
    }
    // --- Pair table: lo16 = i<<10, hi16 = (j<<10)|(j&7), i-major triu order ---
    for (int idx = tid; idx < NK; idx += THREADS) {
        int kk = idx, i = 0, len = 39;
        while (kk >= len) { kk -= len; ++i; --len; }
        const int j = i + 1 + kk;
        ijA[idx] = ((unsigned)((j << 10) | (j & 7)) << 16) | (unsigned)(i << 10);
    }
    __syncthreads();

    const int ww = (tid >> 6) + 8 * khalf;              // global wave id 0..15
    const int l = tid & 63;
    const int b = l & 15;
    const int h = l >> 4;

    const int ps = 2 * ((195 * ww) >> 4);
    const int pe = 2 * ((195 * (ww + 1)) >> 4);

    const short8* wf = (const short8*)wfrag;            // idx = k*128 + half*64 + l

    // vi f32 register cache (reloaded only at i-group boundaries)
    int cur_iod = -1;
    float vif0 = 0, vif1 = 0, vif2 = 0, vif3 = 0, vif4 = 0, vif5 = 0, vif6 = 0, vif7 = 0;
    const int glo = b + 16 * (h >> 1);                  // granule for e = 4h..4h+3
    const int ghi = b + 16 * (2 + (h >> 1));            // granule for e = 16+4h..
    const int esub = (h & 1) * 8;

    // Prologue: W fragments (A: e-half0, e-half1) for the first pair-pair.
    short8 ca00 = wf[(size_t)(2 * ps) * 128 + l];
    short8 ca01 = wf[(size_t)(2 * ps) * 128 + 64 + l];
    short8 ca10 = wf[(size_t)(2 * ps + 1) * 128 + l];
    short8 ca11 = wf[(size_t)(2 * ps + 1) * 128 + 64 + l];

    for (int pp = ps; pp < pe; ++pp) {
        short8 na00{}, na01{}, na10{}, na11{};
        if (pp + 1 < pe) {                              // uniform prefetch branch
            const size_t k0 = (size_t)(2 * (pp + 1)) * 128;
            na00 = wf[k0 + l];
            na01 = wf[k0 + 64 + l];
            na10 = wf[k0 + 128 + l];
            na11 = wf[k0 + 192 + l];
        }
        const uint2 ij2 = *(const uint2*)(ijA + 2 * pp);
        float pf0, pf1;
#pragma unroll
        for (int kk = 0; kk < 2; ++kk) {
            const unsigned ij = kk ? ij2.y : ij2.x;
            const int iod = __builtin_amdgcn_readfirstlane((int)(ij & 0xffffu)); // = i<<10
            if (iod != cur_iod) {                       // scalar branch, rare
                cur_iod = iod;
                const int i7 = (iod >> 10) & 7;
                const ushort4_t lo = *(const ushort4_t*)(embT + iod + ((glo ^ i7) << 4) + esub);
                const ushort4_t hi4 = *(const ushort4_t*)(embT + iod + ((ghi ^ i7) << 4) + esub);
                vif0 = bf2f(lo[0]);  vif1 = bf2f(lo[1]);
                vif2 = bf2f(lo[2]);  vif3 = bf2f(lo[3]);
                vif4 = bf2f(hi4[0]); vif5 = bf2f(hi4[1]);
                vif6 = bf2f(hi4[2]); vif7 = bf2f(hi4[3]);
            }
            const unsigned jj = ij >> 16;
            const int vaddr = (int)(jj & 0xFC00u) + ((l ^ (int)(jj & 7u)) << 4);
            const short8 vjf = *(const short8*)(embT + vaddr);  // B-frag, conflict-free
            const short8 a0 = kk ? ca10 : ca00;
            const short8 a1 = kk ? ca11 : ca01;
            f32x4 t0 = {};
            f32x4 t1 = {};
            t0 = __builtin_amdgcn_mfma_f32_16x16x32_bf16(a0, vjf, t0, 0, 0, 0); // e 0..15
            t1 = __builtin_amdgcn_mfma_f32_16x16x32_bf16(a1, vjf, t1, 0, 0, 0); // e 16..31
            // lane rows: e = 4h+r (t0), 16+4h+r (t1); vi values are register-cached f32
            float p = t0[0] * vif0 + t0[1] * vif1 + t0[2] * vif2 + t0[3] * vif3
                    + t1[0] * vif4 + t1[1] * vif5 + t1[2] * vif6 + t1[3] * vif7;
            p += __shfl_xor(p, 16);                     // reduce over the 4 h-groups
            p += __shfl_xor(p, 32);
            if (kk) pf1 = p; else pf0 = p;
        }
        if (l < 16) {
            float2 st; st.x = pf0; st.y = pf1;
            *(float2*)(out + (size_t)(b0 + b) * NK + 2 * pp) = st;
        }
        ca00 = na00; ca01 = na01; ca10 = na10; ca11 = na11;
    }
}

extern "C" void kernel_launch(void* const* d_in, const int* in_sizes, int n_in,
                              void* d_out, int out_size, void* d_ws, size_t ws_size,
                              hipStream_t stream) {
    const float* emb = (const float*)d_in[0];
    const float* W   = (const float*)d_in[1];
    float* out = (float*)d_out;
    unsigned short* wfrag = (unsigned short*)d_ws;       // 780*1024*2 B = 1.6 MB scratch

    wprep_kernel<<<dim3(NK), dim3(128), 0, stream>>>(W, wfrag);
    bil_kernel<<<dim3((8192 / BT) * KSPLIT), dim3(THREADS), 0, stream>>>(emb, wfrag, out);
}

// Round 4
// 44.041 us; speedup vs baseline: 1.4310x; 1.4310x over previous
//
#include <hip/hip_runtime.h>
#include <cstdint>
#include <cstddef>

typedef __attribute__((ext_vector_type(8))) short short8;
typedef __attribute__((ext_vector_type(4))) unsigned short ushort4_t;
typedef __attribute__((ext_vector_type(4))) float f32x4;

#define NF 40
#define NK 780           // 40*39/2 pairs
#define BT 32            // batch rows per block
#define THREADS 1024     // 16 waves

__device__ __forceinline__ unsigned short f2bf(float f) {
    unsigned int u = __float_as_uint(f);
    u = (u + 0x7fffu + ((u >> 16) & 1u)) >> 16;
    return (unsigned short)u;
}
__device__ __forceinline__ float bf2f(unsigned short x) {
    return __uint_as_float(((unsigned int)x) << 16);
}

// wfrag[k][half][l][t] = bf16( W[k][ (l&15)+16*half ][ 8*(l>>4)+t ] )
// = A-fragment (rows e, K-dim f) for mfma_f32_16x16x32_bf16; half = e-half.
__global__ __launch_bounds__(128) void wprep_kernel(const float* __restrict__ W,
                                                    unsigned short* __restrict__ wfrag) {
    const int k = blockIdx.x, t = threadIdx.x;
    const int half = t >> 6, l = t & 63;
    const int e = (l & 15) + 16 * half;
    const int f0 = 8 * (l >> 4);
    const float* src = W + (size_t)k * 1024 + e * 32 + f0;
    const float4 x0 = *(const float4*)src;
    const float4 x1 = *(const float4*)(src + 4);
    short8 v;
    v[0] = (short)f2bf(x0.x); v[1] = (short)f2bf(x0.y);
    v[2] = (short)f2bf(x0.z); v[3] = (short)f2bf(x0.w);
    v[4] = (short)f2bf(x1.x); v[5] = (short)f2bf(x1.y);
    v[6] = (short)f2bf(x1.z); v[7] = (short)f2bf(x1.w);
    *(short8*)(wfrag + (size_t)k * 1024 + half * 512 + l * 8) = v;
}

// embT granule (field, g): g = (b + 32*fq) ^ (field&7), holds bf16 of
// emb[b0+b][field][8*fq .. 8*fq+7]. XOR spreads bank-quads on both sides.

// reload the f32 vi register cache for row-pair (bq, bq+16) at field ii
#define RELOAD_VI()                                                                     \
    {                                                                                   \
        const int i7 = ii & 7;                                                          \
        const char* ibase = embT + (ii << 11) + eoff;                                   \
        const ushort4_t ra = *(const ushort4_t*)(ibase + (((bq      + fqlo32) ^ i7) << 4)); \
        const ushort4_t rb = *(const ushort4_t*)(ibase + (((bq + 64 + fqlo32) ^ i7) << 4)); \
        const ushort4_t rc = *(const ushort4_t*)(ibase + (((bq + 16 + fqlo32) ^ i7) << 4)); \
        const ushort4_t rd = *(const ushort4_t*)(ibase + (((bq + 80 + fqlo32) ^ i7) << 4)); \
        vf00 = bf2f(ra[0]); vf01 = bf2f(ra[1]); vf02 = bf2f(ra[2]); vf03 = bf2f(ra[3]); \
        vf04 = bf2f(rb[0]); vf05 = bf2f(rb[1]); vf06 = bf2f(rb[2]); vf07 = bf2f(rb[3]); \
        vf10 = bf2f(rc[0]); vf11 = bf2f(rc[1]); vf12 = bf2f(rc[2]); vf13 = bf2f(rc[3]); \
        vf14 = bf2f(rd[0]); vf15 = bf2f(rd[1]); vf16 = bf2f(rd[2]); vf17 = bf2f(rd[3]); \
    }

// one k: tmp[e,b] = W[k]·vj  (4 MFMAs: 2 e-halves x 2 b-halves), then dot with vi
#define KSTEP(AE0, AE1, OREG)                                                           \
    {                                                                                   \
        const int j7 = jj & 7;                                                          \
        const char* jbase = embT + (jj << 11);                                          \
        const short8 vj0 = *(const short8*)(jbase + (((bq      + fq32) ^ j7) << 4));    \
        const short8 vj1 = *(const short8*)(jbase + (((bq + 16 + fq32) ^ j7) << 4));    \
        f32x4 t00 = {}, t01 = {}, t10 = {}, t11 = {};                                   \
        t00 = __builtin_amdgcn_mfma_f32_16x16x32_bf16(AE0, vj0, t00, 0, 0, 0);          \
        t10 = __builtin_amdgcn_mfma_f32_16x16x32_bf16(AE1, vj0, t10, 0, 0, 0);          \
        t01 = __builtin_amdgcn_mfma_f32_16x16x32_bf16(AE0, vj1, t01, 0, 0, 0);          \
        t11 = __builtin_amdgcn_mfma_f32_16x16x32_bf16(AE1, vj1, t11, 0, 0, 0);          \
        float p0 = t00[0]*vf00 + t00[1]*vf01 + t00[2]*vf02 + t00[3]*vf03                \
                 + t10[0]*vf04 + t10[1]*vf05 + t10[2]*vf06 + t10[3]*vf07;               \
        float p1 = t01[0]*vf10 + t01[1]*vf11 + t01[2]*vf12 + t01[3]*vf13                \
                 + t11[0]*vf14 + t11[1]*vf15 + t11[2]*vf16 + t11[3]*vf17;               \
        p0 += __shfl_xor(p0, 16); p0 += __shfl_xor(p0, 32);                             \
        p1 += __shfl_xor(p1, 16); p1 += __shfl_xor(p1, 32);                             \
        OREG = (l & 16) ? p1 : p0;                                                      \
        ++jj;                                                                           \
        if (jj == NF) { ++ii; jj = ii + 1; RELOAD_VI(); }                               \
    }

__global__ __launch_bounds__(THREADS, 4) void bil_kernel(const float* __restrict__ emb,
                                                         const unsigned short* __restrict__ wfrag,
                                                         float* __restrict__ out) {
    __shared__ __align__(16) char embT[NF * 2048];   // 81920 B (gfx950: 160 KiB/WG max)

    const int tid = threadIdx.x;
    const int b0 = blockIdx.x * BT;

    // --- Stage 32-row tile: coalesced 32B global reads, conflict-free swizzled LDS writes ---
    for (int u = tid; u < BT * 160; u += THREADS) {  // exactly 5 iterations
        const int bb = u / 160;
        const int t = u - 160 * bb;
        const int field = t >> 2;
        const int fq = t & 3;
        const float* src = emb + (size_t)(b0 + bb) * (NF * 32) + field * 32 + 8 * fq;
        const float4 x0 = *(const float4*)src;
        const float4 x1 = *(const float4*)(src + 4);
        short8 v;
        v[0] = (short)f2bf(x0.x); v[1] = (short)f2bf(x0.y);
        v[2] = (short)f2bf(x0.z); v[3] = (short)f2bf(x0.w);
        v[4] = (short)f2bf(x1.x); v[5] = (short)f2bf(x1.y);
        v[6] = (short)f2bf(x1.z); v[7] = (short)f2bf(x1.w);
        const int g = (bb + 32 * fq) ^ (field & 7);
        *(short8*)(embT + field * 2048 + g * 16) = v;
    }
    __syncthreads();

    const int ww = tid >> 6;            // wave 0..15
    const int l = tid & 63;
    const int bq = l & 15;
    const int h = l >> 4;
    const int fq32 = h << 5;            // vj granule fq*32
    const int fqlo32 = (h >> 1) << 5;   // vi granule fq*32 (e-low block)
    const int eoff = (h & 1) * 8;       // byte offset within vi granule

    // Even-aligned contiguous pair-pair range per wave (lengths 24 or 26).
    const int ps = 2 * ((195 * ww) >> 4);
    const int pe = 2 * ((195 * (ww + 1)) >> 4);

    // initial (ii, jj) for k = 2*ps  (i-major triu order)
    int ii = 0, jj;
    {
        int kk = 2 * ps, len = 39;
        while (kk >= len) { kk -= len; ++ii; --len; }
        jj = ii + 1 + kk;
    }

    float vf00, vf01, vf02, vf03, vf04, vf05, vf06, vf07;
    float vf10, vf11, vf12, vf13, vf14, vf15, vf16, vf17;
    RELOAD_VI();

    const short8* wf = (const short8*)wfrag;   // idx = k*128 + half*64 + l

    // Prologue: W fragments for the first group (4 k's).
    size_t gb = (size_t)(2 * ps) * 128;
    short8 c0e0 = wf[gb + l],       c0e1 = wf[gb + 64 + l];
    short8 c1e0 = wf[gb + 128 + l], c1e1 = wf[gb + 192 + l];
    short8 c2e0 = wf[gb + 256 + l], c2e1 = wf[gb + 320 + l];
    short8 c3e0 = wf[gb + 384 + l], c3e1 = wf[gb + 448 + l];

    for (int pg = ps; pg < pe; pg += 2) {       // group = 2 pair-pairs = 4 k
        const bool more = (pg + 2) < pe;
        short8 n0e0 = {}, n0e1 = {}, n1e0 = {}, n1e1 = {};
        short8 n2e0 = {}, n2e1 = {}, n3e0 = {}, n3e1 = {};
        if (more) {                              // prefetch next group's 8 fragments
            const size_t nb = (size_t)(2 * (pg + 2)) * 128;
            n0e0 = wf[nb + l];       n0e1 = wf[nb + 64 + l];
            n1e0 = wf[nb + 128 + l]; n1e1 = wf[nb + 192 + l];
            n2e0 = wf[nb + 256 + l]; n2e1 = wf[nb + 320 + l];
            n3e0 = wf[nb + 384 + l]; n3e1 = wf[nb + 448 + l];
        }
        float o0, o1, o2, o3;
        KSTEP(c0e0, c0e1, o0);
        KSTEP(c1e0, c1e1, o1);
        KSTEP(c2e0, c2e1, o2);
        KSTEP(c3e0, c3e1, o3);
        if (l < 32) {                            // lane l owns row b0+l; 16B aligned store
            float4 st; st.x = o0; st.y = o1; st.z = o2; st.w = o3;
            *(float4*)(out + (size_t)(b0 + l) * NK + 2 * pg) = st;
        }
        if (more) {
            c0e0 = n0e0; c0e1 = n0e1; c1e0 = n1e0; c1e1 = n1e1;
            c2e0 = n2e0; c2e1 = n2e1; c3e0 = n3e0; c3e1 = n3e1;
        }
    }
}

extern "C" void kernel_launch(void* const* d_in, const int* in_sizes, int n_in,
                              void* d_out, int out_size, void* d_ws, size_t ws_size,
                              hipStream_t stream) {
    const float* emb = (const float*)d_in[0];
    const float* W   = (const float*)d_in[1];
    float* out = (float*)d_out;
    unsigned short* wfrag = (unsigned short*)d_ws;   // 780*1024*2 B = 1.6 MB scratch

    wprep_kernel<<<dim3(NK), dim3(128), 0, stream>>>(W, wfrag);
    bil_kernel<<<dim3(8192 / BT), dim3(THREADS), 0, stream>>>(emb, wfrag, out);
}